// Round 4
// baseline (243.964 us; speedup 1.0000x reference)
//
#include <hip/hip_runtime.h>

#define L_SEQ 2048
#define NB    2
#define DMOD  1024
#define DIN   2048
#define NST   16
#define NROWS (NB*L_SEQ)   // 4096
#define CL    64
#define NC    (L_SEQ/CL)   // 32

typedef unsigned short u16;
typedef _Float16 half8 __attribute__((ext_vector_type(8)));
typedef float f32x4 __attribute__((ext_vector_type(4)));
typedef short short8 __attribute__((ext_vector_type(8)));

__device__ __forceinline__ float siluf(float v){ return v / (1.f + __expf(-v)); }
__device__ __forceinline__ u16 f2h_bits(float v){ _Float16 h = (_Float16)v; return __builtin_bit_cast(u16, h); }
__device__ __forceinline__ float h2f(u16 v){ return (float)__builtin_bit_cast(_Float16, v); }
__device__ __forceinline__ float fexp2(float x){
#if __has_builtin(__builtin_amdgcn_exp2f)
    return __builtin_amdgcn_exp2f(x);
#else
    return __expf(x * 0.69314718056f);
#endif
}

// async global->LDS, 16B per lane; lds base must be wave-uniform
__device__ __forceinline__ void gload16(const u16* g, u16* l)
{
    __builtin_amdgcn_global_load_lds(
        (const __attribute__((address_space(1))) void*)g,
        (__attribute__((address_space(3))) void*)l,
        16, 0, 0);
}

// ---------------- fp32 -> fp16 convert (vec4) ----------------
__global__ __launch_bounds__(256)
void f32_to_f16(const float* __restrict__ in, u16* __restrict__ out, int n4)
{
    int i = blockIdx.x * 256 + threadIdx.x;
    if (i >= n4) return;
    float4 v = ((const float4*)in)[i];
    ushort4 o;
    o.x = f2h_bits(v.x); o.y = f2h_bits(v.y); o.z = f2h_bits(v.z); o.w = f2h_bits(v.w);
    *(ushort4*)&out[(size_t)i * 4] = o;
}

// ---------------- transpose fp32 [R][C] -> fp16 [C][R] ----------------
__global__ __launch_bounds__(256)
void transpose_to_f16(const float* __restrict__ in, u16* __restrict__ outT, int R, int C)
{
    __shared__ float s[64][65];
    int r0 = blockIdx.y * 64, c0 = blockIdx.x * 64;
    int tc = threadIdx.x & 63, ty = threadIdx.x >> 6;
    #pragma unroll
    for (int j = 0; j < 16; j++) {
        int r = ty + j * 4;
        s[r][tc] = in[(size_t)(r0 + r) * C + c0 + tc];
    }
    __syncthreads();
    #pragma unroll
    for (int j = 0; j < 16; j++) {
        int nn = ty + j * 4;
        outT[(size_t)(c0 + nn) * R + r0 + tc] = f2h_bits(s[tc][nn]);
    }
}

// ---------------- MFMA GEMM, m97 structure: 128x128 tile, BK=32, global_load_lds ----------------
// EPI==0: C0 = fp32 [M][N]
// EPI==1: split at N/2: col<half -> C0h (u16) ; else C1h = silu (u16)
template<int EPI>
__global__ __launch_bounds__(256)
void gemm_mfma(const u16* __restrict__ A, const u16* __restrict__ Bt,
               void* __restrict__ C0v, void* __restrict__ C1v,
               int M, int N, int K)
{
    __shared__ __align__(16) u16 As[128 * 32];   // [row][32], linear (gload_lds order)
    __shared__ __align__(16) u16 Bs[128 * 32];
    const int tid  = threadIdx.x;
    const int lane = tid & 63;
    const int wid  = tid >> 6;
    const int wm   = wid >> 1, wn = wid & 1;
    const int bm = blockIdx.y * 128, bn = blockIdx.x * 128;

    // staging: call c = wid*2+j writes LDS bytes [c*1024, c*1024+1024) = rows c*16..c*16+15
    // lane l -> row c*16 + (l>>2), 16B unit (l&3)
    const int sunit = lane & 3;
    const int srow  = lane >> 2;
    const u16* Ag = A  + (size_t)bm * K + sunit * 8;
    const u16* Bg = Bt + (size_t)bn * K + sunit * 8;

    f32x4 acc[4][4];
    #pragma unroll
    for (int i = 0; i < 4; i++)
        #pragma unroll
        for (int j = 0; j < 4; j++)
            acc[i][j] = (f32x4){0.f, 0.f, 0.f, 0.f};

    for (int k0 = 0; k0 < K; k0 += 32) {
        __syncthreads();   // prior iteration's LDS reads complete before overwrite
        #pragma unroll
        for (int j = 0; j < 2; j++) {
            int row = wid * 32 + j * 16 + srow;
            gload16(Ag + (size_t)row * K + k0, &As[(wid * 2 + j) * 512]);
            gload16(Bg + (size_t)row * K + k0, &Bs[(wid * 2 + j) * 512]);
        }
        __syncthreads();   // compiler drains vmcnt(0): staged data visible

        half8 af[4], bf[4];
        #pragma unroll
        for (int mi = 0; mi < 4; mi++) {
            int row = wm * 64 + mi * 16 + (lane & 15);
            af[mi] = *(const half8*)&As[row * 32 + (lane >> 4) * 8];
        }
        #pragma unroll
        for (int ni = 0; ni < 4; ni++) {
            int row = wn * 64 + ni * 16 + (lane & 15);
            bf[ni] = *(const half8*)&Bs[row * 32 + (lane >> 4) * 8];
        }
        #pragma unroll
        for (int mi = 0; mi < 4; mi++)
            #pragma unroll
            for (int ni = 0; ni < 4; ni++)
                acc[mi][ni] = __builtin_amdgcn_mfma_f32_16x16x32_f16(af[mi], bf[ni], acc[mi][ni], 0, 0, 0);
    }

    const int cr = (lane >> 4) * 4;
    const int cc = lane & 15;
    #pragma unroll
    for (int mi = 0; mi < 4; mi++) {
        #pragma unroll
        for (int ni = 0; ni < 4; ni++) {
            #pragma unroll
            for (int q = 0; q < 4; q++) {
                int row = bm + wm * 64 + mi * 16 + cr + q;
                int col = bn + wn * 64 + ni * 16 + cc;
                float v = acc[mi][ni][q];
                if (EPI == 0) {
                    ((float*)C0v)[(size_t)row * N + col] = v;
                } else {
                    int half = N >> 1;
                    if (col < half) ((u16*)C0v)[(size_t)row * half + col] = f2h_bits(v);
                    else            ((u16*)C1v)[(size_t)row * half + col - half] = f2h_bits(siluf(v));
                }
            }
        }
    }
}

// ---------------- depthwise causal conv (4 taps) + bias + SiLU, fp16 io ----------------
__global__ __launch_bounds__(256)
void conv_silu16(const u16* __restrict__ xin16, const float* __restrict__ cw,
                 const float* __restrict__ cb, u16* __restrict__ xc16)
{
    int idx = blockIdx.x * 256 + threadIdx.x;      // (b,t,d8): NB*L*DIN/8
    int d8 = idx & 255;
    int t  = (idx >> 8) & (L_SEQ - 1);
    int b  = idx >> 19;
    int d  = d8 << 3;
    const float4* cw4 = (const float4*)cw;
    float4 w[8];
    #pragma unroll
    for (int j = 0; j < 8; j++) w[j] = cw4[d + j];
    float acc[8];
    {
        float4 b0 = *(const float4*)&cb[d];
        float4 b1 = *(const float4*)&cb[d + 4];
        acc[0]=b0.x; acc[1]=b0.y; acc[2]=b0.z; acc[3]=b0.w;
        acc[4]=b1.x; acc[5]=b1.y; acc[6]=b1.z; acc[7]=b1.w;
    }
    #pragma unroll
    for (int k = 0; k < 4; k++) {
        int tt = t + k - 3;
        if (tt >= 0) {
            short8 v = *(const short8*)&xin16[((size_t)(b * L_SEQ + tt)) * DIN + d];
            #pragma unroll
            for (int j = 0; j < 8; j++)
                acc[j] = fmaf(h2f((u16)v[j]), (&w[j].x)[k], acc[j]);
        }
    }
    short8 o;
    #pragma unroll
    for (int j = 0; j < 8; j++) o[j] = (short)f2h_bits(siluf(acc[j]));
    *(short8*)&xc16[(size_t)idx * 8] = o;
}

// ---------------- W_x (2048x33 fp32) -> WxT16 [48][2048] fp16, zero-padded ----------------
__global__ __launch_bounds__(256)
void transpose_wx16(const float* __restrict__ Wx, u16* __restrict__ WxT16)
{
    int idx = blockIdx.x * 256 + threadIdx.x;      // 48*2048
    int n = idx >> 11, k = idx & 2047;
    float v = (n < 33) ? Wx[k * 33 + n] : 0.f;
    WxT16[idx] = f2h_bits(v);
}

// ---------------- GEMM2: [4096][2048] @ [48][2048]^T, K-split 8, tile M=64 ----------------
__global__ __launch_bounds__(256)
void gemm2_mfma(const u16* __restrict__ A, const u16* __restrict__ Bt, float* __restrict__ pb)
{
    __shared__ __align__(16) u16 As[64 * 64];
    __shared__ __align__(16) u16 Bs[48 * 64];
    const int tid = threadIdx.x, lane = tid & 63, w = tid >> 6;
    const int bm = blockIdx.x * 64;
    const int kz = blockIdx.y;
    const int arow = tid >> 2;          // 0..63
    const int au   = (tid & 3) << 1;    // unit pair
    f32x4 acc[3];
    acc[0] = acc[1] = acc[2] = (f32x4){0.f, 0.f, 0.f, 0.f};

    for (int it = 0; it < 4; ++it) {
        const int k0 = kz * 256 + it * 64;
        short8 ra0 = *(const short8*)&A[(size_t)(bm + arow) * DIN + k0 + au * 8];
        short8 ra1 = *(const short8*)&A[(size_t)(bm + arow) * DIN + k0 + (au + 1) * 8];
        short8 rb0, rb1;
        if (tid < 192) {
            rb0 = *(const short8*)&Bt[(size_t)arow * DIN + k0 + au * 8];
            rb1 = *(const short8*)&Bt[(size_t)arow * DIN + k0 + (au + 1) * 8];
        }
        __syncthreads();
        {
            int s0 = au ^ (arow & 7), s1 = (au + 1) ^ (arow & 7);
            *(short8*)&As[arow * 64 + s0 * 8] = ra0;
            *(short8*)&As[arow * 64 + s1 * 8] = ra1;
            if (tid < 192) {
                *(short8*)&Bs[arow * 64 + s0 * 8] = rb0;
                *(short8*)&Bs[arow * 64 + s1 * 8] = rb1;
            }
        }
        __syncthreads();
        #pragma unroll
        for (int kk = 0; kk < 2; kk++) {
            int r = w * 16 + (lane & 15);
            int sl = (kk * 4 + (lane >> 4)) ^ (r & 7);
            half8 af = *(const half8*)&As[r * 64 + sl * 8];
            #pragma unroll
            for (int ni = 0; ni < 3; ni++) {
                int br = ni * 16 + (lane & 15);
                int bsl = (kk * 4 + (lane >> 4)) ^ (br & 7);
                half8 bf = *(const half8*)&Bs[br * 64 + bsl * 8];
                acc[ni] = __builtin_amdgcn_mfma_f32_16x16x32_f16(af, bf, acc[ni], 0, 0, 0);
            }
        }
    }
    #pragma unroll
    for (int ni = 0; ni < 3; ni++) {
        #pragma unroll
        for (int q = 0; q < 4; q++) {
            int row = bm + w * 16 + (lane >> 4) * 4 + q;
            int col = ni * 16 + (lane & 15);
            pb[((size_t)kz * NROWS + row) * 48 + col] = acc[ni][q];
        }
    }
}

// ---------------- GEMM2 reduce: sum 8 partials, softplus col0, split B/C ----------------
__global__ __launch_bounds__(256)
void gemm2_reduce(const float* __restrict__ pb, float* __restrict__ delta,
                  float* __restrict__ Bm, float* __restrict__ Cm)
{
    int idx = blockIdx.x * 256 + threadIdx.x;      // 4096*48
    int row = idx / 48, col = idx - row * 48;
    float s = 0.f;
    #pragma unroll
    for (int kz = 0; kz < 8; kz++) s += pb[(size_t)kz * NROWS * 48 + idx];
    if (col == 0)       delta[row] = fmaxf(s, 0.f) + log1pf(__expf(-fabsf(s)));
    else if (col < 17)  Bm[row * NST + col - 1]  = s;
    else if (col < 33)  Cm[row * NST + col - 17] = s;
}

// ---------------- scan pass 1: thread-per-d, h[16] in regs ----------------
__global__ __launch_bounds__(256)
void scan_part1_reg(const u16* __restrict__ xc16, const float* __restrict__ delta,
                    const float* __restrict__ Bm, const float* __restrict__ A_log,
                    float* __restrict__ h_loc, float* __restrict__ Pc)
{
    const int b = blockIdx.z, c = blockIdx.y;
    const int d = blockIdx.x * 256 + threadIdx.x;
    float ka[16];
    {
        const float4* Av = (const float4*)(A_log + (size_t)d * 16);
        #pragma unroll
        for (int q = 0; q < 4; q++) {
            float4 a = Av[q];
            ka[q*4+0] = -__expf(a.x) * 1.44269504f;
            ka[q*4+1] = -__expf(a.y) * 1.44269504f;
            ka[q*4+2] = -__expf(a.z) * 1.44269504f;
            ka[q*4+3] = -__expf(a.w) * 1.44269504f;
        }
    }
    float h[16];
    #pragma unroll
    for (int n = 0; n < 16; n++) h[n] = 0.f;
    float S = 0.f;
    const int rowbase = b * L_SEQ + c * CL;
    #pragma unroll 2
    for (int t = 0; t < CL; ++t) {
        const int rowg = rowbase + t;
        const float dt = delta[rowg];
        const float4* Bv = (const float4*)(Bm + (size_t)rowg * 16);
        float4 b0 = Bv[0], b1 = Bv[1], b2 = Bv[2], b3 = Bv[3];
        float bb[16] = {b0.x,b0.y,b0.z,b0.w, b1.x,b1.y,b1.z,b1.w,
                        b2.x,b2.y,b2.z,b2.w, b3.x,b3.y,b3.z,b3.w};
        const float xt = h2f(xc16[(size_t)rowg * DIN + d]);
        const float dtx = dt * xt;
        S += dt;
        #pragma unroll
        for (int n = 0; n < 16; n++) {
            float a = fexp2(dt * ka[n]);
            h[n] = fmaf(a, h[n], bb[n] * dtx);
        }
    }
    float* hp = h_loc + (((size_t)(b * NC + c) * DIN) + d) * 16;
    float* pp = Pc    + (((size_t)(b * NC + c) * DIN) + d) * 16;
    #pragma unroll
    for (int q = 0; q < 4; q++) {
        *(float4*)&hp[q*4] = (float4){h[q*4+0], h[q*4+1], h[q*4+2], h[q*4+3]};
        *(float4*)&pp[q*4] = (float4){fexp2(S*ka[q*4+0]), fexp2(S*ka[q*4+1]),
                                      fexp2(S*ka[q*4+2]), fexp2(S*ka[q*4+3])};
    }
}

// ---------------- scan pass 2: sequential carry across chunks ----------------
__global__ __launch_bounds__(256)
void scan_carry(const float* __restrict__ h_loc, const float* __restrict__ Pc,
                float* __restrict__ H_in)
{
    int gid = blockIdx.x * 256 + threadIdx.x;      // NB*DIN*NST = 65536
    int b = gid >> 15, r = gid & 32767;
    float H = 0.f;
    for (int c = 0; c < NC; ++c) {
        size_t idx = ((size_t)(b * NC + c) << 15) + r;
        H_in[idx] = H;
        H = fmaf(Pc[idx], H, h_loc[idx]);
    }
}

// ---------------- scan pass 3: thread-per-d, fused epilogue -> y fp16 ----------------
__global__ __launch_bounds__(256)
void scan_part3_reg(const u16* __restrict__ xc16, const float* __restrict__ delta,
                    const float* __restrict__ Bm, const float* __restrict__ Cm,
                    const float* __restrict__ A_log, const float* __restrict__ Dp,
                    const u16* __restrict__ res16, const float* __restrict__ H_in,
                    u16* __restrict__ yh)
{
    const int b = blockIdx.z, c = blockIdx.y;
    const int d = blockIdx.x * 256 + threadIdx.x;
    float ka[16];
    {
        const float4* Av = (const float4*)(A_log + (size_t)d * 16);
        #pragma unroll
        for (int q = 0; q < 4; q++) {
            float4 a = Av[q];
            ka[q*4+0] = -__expf(a.x) * 1.44269504f;
            ka[q*4+1] = -__expf(a.y) * 1.44269504f;
            ka[q*4+2] = -__expf(a.z) * 1.44269504f;
            ka[q*4+3] = -__expf(a.w) * 1.44269504f;
        }
    }
    float h[16];
    {
        const float4* Hv = (const float4*)(H_in + (((size_t)(b * NC + c) * DIN) + d) * 16);
        #pragma unroll
        for (int q = 0; q < 4; q++) {
            float4 v = Hv[q];
            h[q*4+0]=v.x; h[q*4+1]=v.y; h[q*4+2]=v.z; h[q*4+3]=v.w;
        }
    }
    const float Dpd = Dp[d];
    const int rowbase = b * L_SEQ + c * CL;
    #pragma unroll 2
    for (int t = 0; t < CL; ++t) {
        const int rowg = rowbase + t;
        const float dt = delta[rowg];
        const float4* Bv = (const float4*)(Bm + (size_t)rowg * 16);
        const float4* Cv = (const float4*)(Cm + (size_t)rowg * 16);
        float4 b0 = Bv[0], b1 = Bv[1], b2 = Bv[2], b3 = Bv[3];
        float4 c0 = Cv[0], c1 = Cv[1], c2 = Cv[2], c3 = Cv[3];
        float bb[16] = {b0.x,b0.y,b0.z,b0.w, b1.x,b1.y,b1.z,b1.w,
                        b2.x,b2.y,b2.z,b2.w, b3.x,b3.y,b3.z,b3.w};
        float cc[16] = {c0.x,c0.y,c0.z,c0.w, c1.x,c1.y,c1.z,c1.w,
                        c2.x,c2.y,c2.z,c2.w, c3.x,c3.y,c3.z,c3.w};
        const float xt = h2f(xc16[(size_t)rowg * DIN + d]);
        const float rt = h2f(res16[(size_t)rowg * DIN + d]);
        const float dtx = dt * xt;
        float y = 0.f;
        #pragma unroll
        for (int n = 0; n < 16; n++) {
            float a = fexp2(dt * ka[n]);
            h[n] = fmaf(a, h[n], bb[n] * dtx);
            y = fmaf(cc[n], h[n], y);
        }
        y = (y + xt * Dpd) * rt;
        yh[(size_t)rowg * DIN + d] = f2h_bits(y);
    }
}

extern "C" void kernel_launch(void* const* d_in, const int* in_sizes, int n_in,
                              void* d_out, int out_size, void* d_ws, size_t ws_size,
                              hipStream_t stream)
{
    const float* x     = (const float*)d_in[0];
    const float* W_in  = (const float*)d_in[1];
    const float* cw    = (const float*)d_in[2];
    const float* cb    = (const float*)d_in[3];
    const float* Wx    = (const float*)d_in[4];
    const float* A_log = (const float*)d_in[5];
    const float* Dp    = (const float*)d_in[6];
    const float* W_out = (const float*)d_in[7];
    float* out = (float*)d_out;
    float* ws  = (float*)d_ws;

    // workspace layout (float slot offsets)
    u16*   xin16 = (u16*)(ws);                     // [4096][2048] u16 ; later y16 alias
    u16*   y16   = (u16*)(ws);
    u16*   res16 = (u16*)(ws + 4194304);           // [4096][2048]
    u16*   xc16  = (u16*)(ws + 8388608);           // [4096][2048]
    u16*   x16   = (u16*)(ws + 12582912);          // [4096][1024] ; later Bt3 alias
    u16*   Bt3   = (u16*)(ws + 12582912);          // [1024][2048]
    u16*   Bt1   = (u16*)(ws + 14680064);          // [4096][1024] ; later pb alias
    float* pb    = ws + 14680064;                  // [8][4096][48]
    u16*   WxT16 = (u16*)(ws + 16777216);          // [48][2048]
    float* delta = ws + 16826368;                  // 4096
    float* Bm    = ws + 16830464;                  // 65536
    float* Cm    = ws + 16896000;                  // 65536
    float* h_loc = ws + 16961536;                  // 2097152
    float* Pc    = ws + 19058688;                  // 2097152
    float* H_in  = ws + 21155840;                  // 2097152 (end 23252992 floats = 93 MB)

    dim3 blk(256);

    // 1) x -> fp16
    f32_to_f16<<<dim3(NROWS * DMOD / 4 / 256), blk, 0, stream>>>(x, x16, NROWS * DMOD / 4);
    // 2) W_in (1024x4096) -> Bt1 (4096x1024) fp16
    transpose_to_f16<<<dim3(4096 / 64, 1024 / 64), blk, 0, stream>>>(W_in, Bt1, DMOD, 2 * DIN);
    // 3) GEMM1 -> xin16 | silu(res)16
    gemm_mfma<1><<<dim3(32, 32), blk, 0, stream>>>(x16, Bt1, xin16, res16, NROWS, 2 * DIN, DMOD);
    // 4) conv + bias + silu (fp16 io)
    conv_silu16<<<dim3(NB * L_SEQ * (DIN / 8) / 256), blk, 0, stream>>>(xin16, cw, cb, xc16);
    // 5) ssm params: W_x^T fp16 (pad 48), MFMA K-split GEMM, reduce+softplus
    transpose_wx16<<<dim3(48 * DIN / 256), blk, 0, stream>>>(Wx, WxT16);
    gemm2_mfma<<<dim3(NROWS / 64, 8), blk, 0, stream>>>(xc16, WxT16, pb);
    gemm2_reduce<<<dim3(NROWS * 48 / 256), blk, 0, stream>>>(pb, delta, Bm, Cm);
    // 6) chunk-parallel scan (thread-per-d, regs), CL=64
    scan_part1_reg<<<dim3(DIN / 256, NC, NB), blk, 0, stream>>>(xc16, delta, Bm, A_log, h_loc, Pc);
    scan_carry<<<dim3(NB * DIN * NST / 256), blk, 0, stream>>>(h_loc, Pc, H_in);
    scan_part3_reg<<<dim3(DIN / 256, NC, NB), blk, 0, stream>>>(xc16, delta, Bm, Cm, A_log, Dp, res16, H_in, y16);
    // 7) W_out (2048x1024) -> Bt3 (1024x2048) fp16
    transpose_to_f16<<<dim3(1024 / 64, 2048 / 64), blk, 0, stream>>>(W_out, Bt3, DIN, DMOD);
    // 8) GEMM3: out = y @ W_out (fp32 out)
    gemm_mfma<0><<<dim3(1024 / 128, NROWS / 128), blk, 0, stream>>>(y16, Bt3, out, nullptr, NROWS, DMOD, DIN);
}

// Round 5
// 229.979 us; speedup vs baseline: 1.0608x; 1.0608x over previous
//
#include <hip/hip_runtime.h>

#define L_SEQ 2048
#define NB    2
#define DMOD  1024
#define DIN   2048
#define NST   16
#define NROWS (NB*L_SEQ)   // 4096
#define CL    64
#define NC    (L_SEQ/CL)   // 32

typedef unsigned short u16;
typedef _Float16 half8 __attribute__((ext_vector_type(8)));
typedef float f32x4 __attribute__((ext_vector_type(4)));
typedef short short8 __attribute__((ext_vector_type(8)));

__device__ __forceinline__ float siluf(float v){ return v / (1.f + __expf(-v)); }
__device__ __forceinline__ u16 f2h_bits(float v){ _Float16 h = (_Float16)v; return __builtin_bit_cast(u16, h); }
__device__ __forceinline__ float h2f(u16 v){ return (float)__builtin_bit_cast(_Float16, v); }
__device__ __forceinline__ float fexp2(float x){
#if __has_builtin(__builtin_amdgcn_exp2f)
    return __builtin_amdgcn_exp2f(x);
#else
    return __expf(x * 0.69314718056f);
#endif
}

// async global->LDS, 16B per lane; lds base must be wave-uniform; dest = base + lane*16
__device__ __forceinline__ void gload16(const u16* g, u16* l)
{
    __builtin_amdgcn_global_load_lds(
        (const __attribute__((address_space(1))) void*)g,
        (__attribute__((address_space(3))) void*)l,
        16, 0, 0);
}

// ---------------- fp32 -> fp16 convert (vec4) ----------------
__global__ __launch_bounds__(256)
void f32_to_f16(const float* __restrict__ in, u16* __restrict__ out, int n4)
{
    int i = blockIdx.x * 256 + threadIdx.x;
    if (i >= n4) return;
    float4 v = ((const float4*)in)[i];
    ushort4 o;
    o.x = f2h_bits(v.x); o.y = f2h_bits(v.y); o.z = f2h_bits(v.z); o.w = f2h_bits(v.w);
    *(ushort4*)&out[(size_t)i * 4] = o;
}

// ---------------- transpose fp32 [R][C] -> fp16 [C][R] ----------------
__global__ __launch_bounds__(256)
void transpose_to_f16(const float* __restrict__ in, u16* __restrict__ outT, int R, int C)
{
    __shared__ float s[64][65];
    int r0 = blockIdx.y * 64, c0 = blockIdx.x * 64;
    int tc = threadIdx.x & 63, ty = threadIdx.x >> 6;
    #pragma unroll
    for (int j = 0; j < 16; j++) {
        int r = ty + j * 4;
        s[r][tc] = in[(size_t)(r0 + r) * C + c0 + tc];
    }
    __syncthreads();
    #pragma unroll
    for (int j = 0; j < 16; j++) {
        int nn = ty + j * 4;
        outT[(size_t)(c0 + nn) * R + r0 + tc] = f2h_bits(s[tc][nn]);
    }
}

// ---------------- MFMA GEMM: 128x128 tile, BK=64, global_load_lds + source-side swizzle ----
// LDS holds As[row][slot] = A[bm+row][k0 + (slot^(row&7))*8 .. +7]  (16B units)
// EPI==0: C0 = fp32 [M][N]
// EPI==1: split at N/2: col<half -> C0h (u16) ; else C1h = silu (u16)
template<int EPI>
__global__ __launch_bounds__(256)
void gemm_mfma(const u16* __restrict__ A, const u16* __restrict__ Bt,
               void* __restrict__ C0v, void* __restrict__ C1v,
               int M, int N, int K)
{
    __shared__ __align__(16) u16 As[128 * 64];   // 16 KB
    __shared__ __align__(16) u16 Bs[128 * 64];   // 16 KB
    const int tid  = threadIdx.x;
    const int lane = tid & 63;
    const int wid  = tid >> 6;
    const int wm   = wid >> 1, wn = wid & 1;
    const int bm = blockIdx.y * 128, bn = blockIdx.x * 128;

    // staging map: call c covers rows c*8..c*8+7 (1 KB); lane l -> row c*8+(l>>3), slot (l&7)
    // source swizzle: global unit = (l&7) ^ ((l>>3)&7)  (row&7 == (l>>3)&7 since c*8 ≡ 0 mod 8)
    const int srow8 = lane >> 3;                 // 0..7
    const int sunit = (lane & 7) ^ srow8;        // pre-swizzled global 16B-unit
    const u16* Ag = A  + (size_t)(bm + srow8) * K + sunit * 8;
    const u16* Bg = Bt + (size_t)(bn + srow8) * K + sunit * 8;

    f32x4 acc[4][4];
    #pragma unroll
    for (int i = 0; i < 4; i++)
        #pragma unroll
        for (int j = 0; j < 4; j++)
            acc[i][j] = (f32x4){0.f, 0.f, 0.f, 0.f};

    for (int k0 = 0; k0 < K; k0 += 64) {
        __syncthreads();   // prior iteration's LDS reads complete before overwrite
        #pragma unroll
        for (int j = 0; j < 4; j++) {
            const int c = wid * 4 + j;           // 0..15
            gload16(Ag + (size_t)(c * 8) * K + k0, &As[c * 512]);
            gload16(Bg + (size_t)(c * 8) * K + k0, &Bs[c * 512]);
        }
        __syncthreads();   // drains vmcnt(0): staged data visible

        #pragma unroll
        for (int kk = 0; kk < 2; kk++) {
            half8 af[4], bf[4];
            #pragma unroll
            for (int mi = 0; mi < 4; mi++) {
                int row  = wm * 64 + mi * 16 + (lane & 15);
                int slot = (kk * 4 + (lane >> 4)) ^ (row & 7);
                af[mi] = *(const half8*)&As[row * 64 + slot * 8];
            }
            #pragma unroll
            for (int ni = 0; ni < 4; ni++) {
                int row  = wn * 64 + ni * 16 + (lane & 15);
                int slot = (kk * 4 + (lane >> 4)) ^ (row & 7);
                bf[ni] = *(const half8*)&Bs[row * 64 + slot * 8];
            }
            #pragma unroll
            for (int mi = 0; mi < 4; mi++)
                #pragma unroll
                for (int ni = 0; ni < 4; ni++)
                    acc[mi][ni] = __builtin_amdgcn_mfma_f32_16x16x32_f16(af[mi], bf[ni], acc[mi][ni], 0, 0, 0);
        }
    }

    const int cr = (lane >> 4) * 4;
    const int cc = lane & 15;
    #pragma unroll
    for (int mi = 0; mi < 4; mi++) {
        #pragma unroll
        for (int ni = 0; ni < 4; ni++) {
            #pragma unroll
            for (int q = 0; q < 4; q++) {
                int row = bm + wm * 64 + mi * 16 + cr + q;
                int col = bn + wn * 64 + ni * 16 + cc;
                float v = acc[mi][ni][q];
                if (EPI == 0) {
                    ((float*)C0v)[(size_t)row * N + col] = v;
                } else {
                    int half = N >> 1;
                    if (col < half) ((u16*)C0v)[(size_t)row * half + col] = f2h_bits(v);
                    else            ((u16*)C1v)[(size_t)row * half + col - half] = f2h_bits(siluf(v));
                }
            }
        }
    }
}

// ---------------- depthwise causal conv (4 taps) + bias + SiLU, fp16 io ----------------
__global__ __launch_bounds__(256)
void conv_silu16(const u16* __restrict__ xin16, const float* __restrict__ cw,
                 const float* __restrict__ cb, u16* __restrict__ xc16)
{
    int idx = blockIdx.x * 256 + threadIdx.x;      // (b,t,d8): NB*L*DIN/8
    int d8 = idx & 255;
    int t  = (idx >> 8) & (L_SEQ - 1);
    int b  = idx >> 19;
    int d  = d8 << 3;
    const float4* cw4 = (const float4*)cw;
    float4 w[8];
    #pragma unroll
    for (int j = 0; j < 8; j++) w[j] = cw4[d + j];
    float acc[8];
    {
        float4 b0 = *(const float4*)&cb[d];
        float4 b1 = *(const float4*)&cb[d + 4];
        acc[0]=b0.x; acc[1]=b0.y; acc[2]=b0.z; acc[3]=b0.w;
        acc[4]=b1.x; acc[5]=b1.y; acc[6]=b1.z; acc[7]=b1.w;
    }
    #pragma unroll
    for (int k = 0; k < 4; k++) {
        int tt = t + k - 3;
        if (tt >= 0) {
            short8 v = *(const short8*)&xin16[((size_t)(b * L_SEQ + tt)) * DIN + d];
            #pragma unroll
            for (int j = 0; j < 8; j++)
                acc[j] = fmaf(h2f((u16)v[j]), (&w[j].x)[k], acc[j]);
        }
    }
    short8 o;
    #pragma unroll
    for (int j = 0; j < 8; j++) o[j] = (short)f2h_bits(siluf(acc[j]));
    *(short8*)&xc16[(size_t)idx * 8] = o;
}

// ---------------- W_x (2048x33 fp32) -> WxT16 [48][2048] fp16, zero-padded ----------------
__global__ __launch_bounds__(256)
void transpose_wx16(const float* __restrict__ Wx, u16* __restrict__ WxT16)
{
    int idx = blockIdx.x * 256 + threadIdx.x;      // 48*2048
    int n = idx >> 11, k = idx & 2047;
    float v = (n < 33) ? Wx[k * 33 + n] : 0.f;
    WxT16[idx] = f2h_bits(v);
}

// ---------------- GEMM2: [4096][2048] @ [48][2048]^T, K-split 8, tile M=64 ----------------
__global__ __launch_bounds__(256)
void gemm2_mfma(const u16* __restrict__ A, const u16* __restrict__ Bt, float* __restrict__ pb)
{
    __shared__ __align__(16) u16 As[64 * 64];
    __shared__ __align__(16) u16 Bs[48 * 64];
    const int tid = threadIdx.x, lane = tid & 63, w = tid >> 6;
    const int bm = blockIdx.x * 64;
    const int kz = blockIdx.y;
    const int arow = tid >> 2;          // 0..63
    const int au   = (tid & 3) << 1;    // unit pair
    f32x4 acc[3];
    acc[0] = acc[1] = acc[2] = (f32x4){0.f, 0.f, 0.f, 0.f};

    for (int it = 0; it < 4; ++it) {
        const int k0 = kz * 256 + it * 64;
        short8 ra0 = *(const short8*)&A[(size_t)(bm + arow) * DIN + k0 + au * 8];
        short8 ra1 = *(const short8*)&A[(size_t)(bm + arow) * DIN + k0 + (au + 1) * 8];
        short8 rb0, rb1;
        if (tid < 192) {
            rb0 = *(const short8*)&Bt[(size_t)arow * DIN + k0 + au * 8];
            rb1 = *(const short8*)&Bt[(size_t)arow * DIN + k0 + (au + 1) * 8];
        }
        __syncthreads();
        {
            int s0 = au ^ (arow & 7), s1 = (au + 1) ^ (arow & 7);
            *(short8*)&As[arow * 64 + s0 * 8] = ra0;
            *(short8*)&As[arow * 64 + s1 * 8] = ra1;
            if (tid < 192) {
                *(short8*)&Bs[arow * 64 + s0 * 8] = rb0;
                *(short8*)&Bs[arow * 64 + s1 * 8] = rb1;
            }
        }
        __syncthreads();
        #pragma unroll
        for (int kk = 0; kk < 2; kk++) {
            int r = w * 16 + (lane & 15);
            int sl = (kk * 4 + (lane >> 4)) ^ (r & 7);
            half8 af = *(const half8*)&As[r * 64 + sl * 8];
            #pragma unroll
            for (int ni = 0; ni < 3; ni++) {
                int br = ni * 16 + (lane & 15);
                int bsl = (kk * 4 + (lane >> 4)) ^ (br & 7);
                half8 bf = *(const half8*)&Bs[br * 64 + bsl * 8];
                acc[ni] = __builtin_amdgcn_mfma_f32_16x16x32_f16(af, bf, acc[ni], 0, 0, 0);
            }
        }
    }
    #pragma unroll
    for (int ni = 0; ni < 3; ni++) {
        #pragma unroll
        for (int q = 0; q < 4; q++) {
            int row = bm + w * 16 + (lane >> 4) * 4 + q;
            int col = ni * 16 + (lane & 15);
            pb[((size_t)kz * NROWS + row) * 48 + col] = acc[ni][q];
        }
    }
}

// ---------------- GEMM2 reduce: sum 8 partials, softplus col0, split B/C ----------------
__global__ __launch_bounds__(256)
void gemm2_reduce(const float* __restrict__ pb, float* __restrict__ delta,
                  float* __restrict__ Bm, float* __restrict__ Cm)
{
    int idx = blockIdx.x * 256 + threadIdx.x;      // 4096*48
    int row = idx / 48, col = idx - row * 48;
    float s = 0.f;
    #pragma unroll
    for (int kz = 0; kz < 8; kz++) s += pb[(size_t)kz * NROWS * 48 + idx];
    if (col == 0)       delta[row] = fmaxf(s, 0.f) + log1pf(__expf(-fabsf(s)));
    else if (col < 17)  Bm[row * NST + col - 1]  = s;
    else if (col < 33)  Cm[row * NST + col - 17] = s;
}

// ---------------- scan pass 1: thread-per-d, h[16] in regs ----------------
__global__ __launch_bounds__(256)
void scan_part1_reg(const u16* __restrict__ xc16, const float* __restrict__ delta,
                    const float* __restrict__ Bm, const float* __restrict__ A_log,
                    float* __restrict__ h_loc, float* __restrict__ Pc)
{
    const int b = blockIdx.z, c = blockIdx.y;
    const int d = blockIdx.x * 256 + threadIdx.x;
    float ka[16];
    {
        const float4* Av = (const float4*)(A_log + (size_t)d * 16);
        #pragma unroll
        for (int q = 0; q < 4; q++) {
            float4 a = Av[q];
            ka[q*4+0] = -__expf(a.x) * 1.44269504f;
            ka[q*4+1] = -__expf(a.y) * 1.44269504f;
            ka[q*4+2] = -__expf(a.z) * 1.44269504f;
            ka[q*4+3] = -__expf(a.w) * 1.44269504f;
        }
    }
    float h[16];
    #pragma unroll
    for (int n = 0; n < 16; n++) h[n] = 0.f;
    float S = 0.f;
    const int rowbase = b * L_SEQ + c * CL;
    #pragma unroll 2
    for (int t = 0; t < CL; ++t) {
        const int rowg = rowbase + t;
        const float dt = delta[rowg];
        const float4* Bv = (const float4*)(Bm + (size_t)rowg * 16);
        float4 b0 = Bv[0], b1 = Bv[1], b2 = Bv[2], b3 = Bv[3];
        float bb[16] = {b0.x,b0.y,b0.z,b0.w, b1.x,b1.y,b1.z,b1.w,
                        b2.x,b2.y,b2.z,b2.w, b3.x,b3.y,b3.z,b3.w};
        const float xt = h2f(xc16[(size_t)rowg * DIN + d]);
        const float dtx = dt * xt;
        S += dt;
        #pragma unroll
        for (int n = 0; n < 16; n++) {
            float a = fexp2(dt * ka[n]);
            h[n] = fmaf(a, h[n], bb[n] * dtx);
        }
    }
    float* hp = h_loc + (((size_t)(b * NC + c) * DIN) + d) * 16;
    float* pp = Pc    + (((size_t)(b * NC + c) * DIN) + d) * 16;
    #pragma unroll
    for (int q = 0; q < 4; q++) {
        *(float4*)&hp[q*4] = (float4){h[q*4+0], h[q*4+1], h[q*4+2], h[q*4+3]};
        *(float4*)&pp[q*4] = (float4){fexp2(S*ka[q*4+0]), fexp2(S*ka[q*4+1]),
                                      fexp2(S*ka[q*4+2]), fexp2(S*ka[q*4+3])};
    }
}

// ---------------- scan pass 2: sequential carry across chunks ----------------
__global__ __launch_bounds__(256)
void scan_carry(const float* __restrict__ h_loc, const float* __restrict__ Pc,
                float* __restrict__ H_in)
{
    int gid = blockIdx.x * 256 + threadIdx.x;      // NB*DIN*NST = 65536
    int b = gid >> 15, r = gid & 32767;
    float H = 0.f;
    for (int c = 0; c < NC; ++c) {
        size_t idx = ((size_t)(b * NC + c) << 15) + r;
        H_in[idx] = H;
        H = fmaf(Pc[idx], H, h_loc[idx]);
    }
}

// ---------------- scan pass 3: thread-per-d, fused epilogue -> y fp16 ----------------
__global__ __launch_bounds__(256)
void scan_part3_reg(const u16* __restrict__ xc16, const float* __restrict__ delta,
                    const float* __restrict__ Bm, const float* __restrict__ Cm,
                    const float* __restrict__ A_log, const float* __restrict__ Dp,
                    const u16* __restrict__ res16, const float* __restrict__ H_in,
                    u16* __restrict__ yh)
{
    const int b = blockIdx.z, c = blockIdx.y;
    const int d = blockIdx.x * 256 + threadIdx.x;
    float ka[16];
    {
        const float4* Av = (const float4*)(A_log + (size_t)d * 16);
        #pragma unroll
        for (int q = 0; q < 4; q++) {
            float4 a = Av[q];
            ka[q*4+0] = -__expf(a.x) * 1.44269504f;
            ka[q*4+1] = -__expf(a.y) * 1.44269504f;
            ka[q*4+2] = -__expf(a.z) * 1.44269504f;
            ka[q*4+3] = -__expf(a.w) * 1.44269504f;
        }
    }
    float h[16];
    {
        const float4* Hv = (const float4*)(H_in + (((size_t)(b * NC + c) * DIN) + d) * 16);
        #pragma unroll
        for (int q = 0; q < 4; q++) {
            float4 v = Hv[q];
            h[q*4+0]=v.x; h[q*4+1]=v.y; h[q*4+2]=v.z; h[q*4+3]=v.w;
        }
    }
    const float Dpd = Dp[d];
    const int rowbase = b * L_SEQ + c * CL;
    #pragma unroll 2
    for (int t = 0; t < CL; ++t) {
        const int rowg = rowbase + t;
        const float dt = delta[rowg];
        const float4* Bv = (const float4*)(Bm + (size_t)rowg * 16);
        const float4* Cv = (const float4*)(Cm + (size_t)rowg * 16);
        float4 b0 = Bv[0], b1 = Bv[1], b2 = Bv[2], b3 = Bv[3];
        float4 c0 = Cv[0], c1 = Cv[1], c2 = Cv[2], c3 = Cv[3];
        float bb[16] = {b0.x,b0.y,b0.z,b0.w, b1.x,b1.y,b1.z,b1.w,
                        b2.x,b2.y,b2.z,b2.w, b3.x,b3.y,b3.z,b3.w};
        float cc[16] = {c0.x,c0.y,c0.z,c0.w, c1.x,c1.y,c1.z,c1.w,
                        c2.x,c2.y,c2.z,c2.w, c3.x,c3.y,c3.z,c3.w};
        const float xt = h2f(xc16[(size_t)rowg * DIN + d]);
        const float rt = h2f(res16[(size_t)rowg * DIN + d]);
        const float dtx = dt * xt;
        float y = 0.f;
        #pragma unroll
        for (int n = 0; n < 16; n++) {
            float a = fexp2(dt * ka[n]);
            h[n] = fmaf(a, h[n], bb[n] * dtx);
            y = fmaf(cc[n], h[n], y);
        }
        y = (y + xt * Dpd) * rt;
        yh[(size_t)rowg * DIN + d] = f2h_bits(y);
    }
}

extern "C" void kernel_launch(void* const* d_in, const int* in_sizes, int n_in,
                              void* d_out, int out_size, void* d_ws, size_t ws_size,
                              hipStream_t stream)
{
    const float* x     = (const float*)d_in[0];
    const float* W_in  = (const float*)d_in[1];
    const float* cw    = (const float*)d_in[2];
    const float* cb    = (const float*)d_in[3];
    const float* Wx    = (const float*)d_in[4];
    const float* A_log = (const float*)d_in[5];
    const float* Dp    = (const float*)d_in[6];
    const float* W_out = (const float*)d_in[7];
    float* out = (float*)d_out;
    float* ws  = (float*)d_ws;

    // workspace layout (float slot offsets)
    u16*   xin16 = (u16*)(ws);                     // [4096][2048] u16 ; later y16 alias
    u16*   y16   = (u16*)(ws);
    u16*   res16 = (u16*)(ws + 4194304);           // [4096][2048]
    u16*   xc16  = (u16*)(ws + 8388608);           // [4096][2048]
    u16*   x16   = (u16*)(ws + 12582912);          // [4096][1024] ; later Bt3 alias
    u16*   Bt3   = (u16*)(ws + 12582912);          // [1024][2048]
    u16*   Bt1   = (u16*)(ws + 14680064);          // [4096][1024] ; later pb alias
    float* pb    = ws + 14680064;                  // [8][4096][48]
    u16*   WxT16 = (u16*)(ws + 16777216);          // [48][2048]
    float* delta = ws + 16826368;                  // 4096
    float* Bm    = ws + 16830464;                  // 65536
    float* Cm    = ws + 16896000;                  // 65536
    float* h_loc = ws + 16961536;                  // 2097152
    float* Pc    = ws + 19058688;                  // 2097152
    float* H_in  = ws + 21155840;                  // 2097152 (end 23252992 floats = 93 MB)

    dim3 blk(256);

    // 1) x -> fp16
    f32_to_f16<<<dim3(NROWS * DMOD / 4 / 256), blk, 0, stream>>>(x, x16, NROWS * DMOD / 4);
    // 2) W_in (1024x4096) -> Bt1 (4096x1024) fp16
    transpose_to_f16<<<dim3(4096 / 64, 1024 / 64), blk, 0, stream>>>(W_in, Bt1, DMOD, 2 * DIN);
    // 3) GEMM1 -> xin16 | silu(res)16
    gemm_mfma<1><<<dim3(32, 32), blk, 0, stream>>>(x16, Bt1, xin16, res16, NROWS, 2 * DIN, DMOD);
    // 4) conv + bias + silu (fp16 io)
    conv_silu16<<<dim3(NB * L_SEQ * (DIN / 8) / 256), blk, 0, stream>>>(xin16, cw, cb, xc16);
    // 5) ssm params: W_x^T fp16 (pad 48), MFMA K-split GEMM, reduce+softplus
    transpose_wx16<<<dim3(48 * DIN / 256), blk, 0, stream>>>(Wx, WxT16);
    gemm2_mfma<<<dim3(NROWS / 64, 8), blk, 0, stream>>>(xc16, WxT16, pb);
    gemm2_reduce<<<dim3(NROWS * 48 / 256), blk, 0, stream>>>(pb, delta, Bm, Cm);
    // 6) chunk-parallel scan (thread-per-d, regs), CL=64
    scan_part1_reg<<<dim3(DIN / 256, NC, NB), blk, 0, stream>>>(xc16, delta, Bm, A_log, h_loc, Pc);
    scan_carry<<<dim3(NB * DIN * NST / 256), blk, 0, stream>>>(h_loc, Pc, H_in);
    scan_part3_reg<<<dim3(DIN / 256, NC, NB), blk, 0, stream>>>(xc16, delta, Bm, Cm, A_log, Dp, res16, H_in, y16);
    // 7) W_out (2048x1024) -> Bt3 (1024x2048) fp16
    transpose_to_f16<<<dim3(1024 / 64, 2048 / 64), blk, 0, stream>>>(W_out, Bt3, DIN, DMOD);
    // 8) GEMM3: out = y @ W_out (fp32 out)
    gemm_mfma<0><<<dim3(1024 / 128, NROWS / 128), blk, 0, stream>>>(y16, Bt3, out, nullptr, NROWS, DMOD, DIN);
}

// Round 6
// 210.866 us; speedup vs baseline: 1.1570x; 1.0906x over previous
//
#include <hip/hip_runtime.h>

#define L_SEQ 2048
#define NB    2
#define DMOD  1024
#define DIN   2048
#define NST   16
#define NROWS (NB*L_SEQ)   // 4096
#define CL    64
#define NC    (L_SEQ/CL)   // 32

typedef unsigned short u16;
typedef _Float16 half8 __attribute__((ext_vector_type(8)));
typedef float f32x4 __attribute__((ext_vector_type(4)));
typedef short short8 __attribute__((ext_vector_type(8)));

__device__ __forceinline__ float siluf(float v){ return v / (1.f + __expf(-v)); }
__device__ __forceinline__ u16 f2h_bits(float v){ _Float16 h = (_Float16)v; return __builtin_bit_cast(u16, h); }
__device__ __forceinline__ float h2f(u16 v){ return (float)__builtin_bit_cast(_Float16, v); }
__device__ __forceinline__ float fexp2(float x){
#if __has_builtin(__builtin_amdgcn_exp2f)
    return __builtin_amdgcn_exp2f(x);
#else
    return __expf(x * 0.69314718056f);
#endif
}

// async global->LDS, 16B per lane; lds base wave-uniform; dest = base + lane*16
__device__ __forceinline__ void gload16(const u16* g, u16* l)
{
    __builtin_amdgcn_global_load_lds(
        (const __attribute__((address_space(1))) void*)g,
        (__attribute__((address_space(3))) void*)l,
        16, 0, 0);
}

// ---------------- fp32 -> fp16 convert (vec4) ----------------
__global__ __launch_bounds__(256)
void f32_to_f16(const float* __restrict__ in, u16* __restrict__ out, int n4)
{
    int i = blockIdx.x * 256 + threadIdx.x;
    if (i >= n4) return;
    float4 v = ((const float4*)in)[i];
    ushort4 o;
    o.x = f2h_bits(v.x); o.y = f2h_bits(v.y); o.z = f2h_bits(v.z); o.w = f2h_bits(v.w);
    *(ushort4*)&out[(size_t)i * 4] = o;
}

// ---------------- transpose fp32 [R][C] -> fp16 [C][R] ----------------
__global__ __launch_bounds__(256)
void transpose_to_f16(const float* __restrict__ in, u16* __restrict__ outT, int R, int C)
{
    __shared__ float s[64][65];
    int r0 = blockIdx.y * 64, c0 = blockIdx.x * 64;
    int tc = threadIdx.x & 63, ty = threadIdx.x >> 6;
    #pragma unroll
    for (int j = 0; j < 16; j++) {
        int r = ty + j * 4;
        s[r][tc] = in[(size_t)(r0 + r) * C + c0 + tc];
    }
    __syncthreads();
    #pragma unroll
    for (int j = 0; j < 16; j++) {
        int nn = ty + j * 4;
        outT[(size_t)(c0 + nn) * R + r0 + tc] = f2h_bits(s[tc][nn]);
    }
}

// ---------------- MFMA GEMM: 128xBN tile, BK=64, gload_lds + src-swizzle, 2-phase dbuf ----
// LDS holds T[row][slot] = G[row][slot ^ (row&7)] (16B units); K-tiles double-buffered.
// EPI==0: C0 = fp32 [M][N]
// EPI==1: split at N/2: col<half -> C0h (u16) ; else C1h = silu (u16)
template<int BN, int EPI>
__global__ __launch_bounds__(256)
void gemm_mfma(const u16* __restrict__ A, const u16* __restrict__ Bt,
               void* __restrict__ C0v, void* __restrict__ C1v,
               int M, int N, int K)
{
    constexpr int NI = BN / 32;                    // B-frags per wave
    __shared__ __align__(16) u16 As0[128 * 64], As1[128 * 64];
    __shared__ __align__(16) u16 Bs0[BN * 64],  Bs1[BN * 64];
    const int tid  = threadIdx.x;
    const int lane = tid & 63;
    const int wid  = tid >> 6;
    const int wm   = wid >> 1, wn = wid & 1;
    const int bm = blockIdx.y * 128, bn = blockIdx.x * BN;

    // staging: call c covers rows c*8..c*8+7; lane l -> row c*8+(l>>3), slot (l&7)
    // source pre-swizzle: global unit = (l&7) ^ (l>>3)
    const int srow8 = lane >> 3;
    const int sunit = (lane & 7) ^ srow8;
    const u16* Ag = A  + (size_t)(bm + srow8) * K + sunit * 8;
    const u16* Bg = Bt + (size_t)(bn + srow8) * K + sunit * 8;

    // fragment read offsets (elements), hoisted; kk=1 = kk=0 ^ 32 (slot-bit XOR only)
    const int fr = lane & 15;
    const int s0 = (((lane >> 4) ^ (lane & 7))) * 8;
    const int aBase = (wm * 64 + fr) * 64 + s0;
    const int bBase = (wn * (BN / 2) + fr) * 64 + s0;

    f32x4 acc[4][NI];
    #pragma unroll
    for (int i = 0; i < 4; i++)
        #pragma unroll
        for (int j = 0; j < NI; j++)
            acc[i][j] = (f32x4){0.f, 0.f, 0.f, 0.f};

    auto STAGE = [&](u16* Ab, u16* Bb, int k0) {
        #pragma unroll
        for (int j = 0; j < 4; j++) {              // A: 16 calls (4/wave)
            int c = wid * 4 + j;
            gload16(Ag + (size_t)(c * 8) * K + k0, Ab + c * 512);
        }
        #pragma unroll
        for (int j = 0; j < NI; j++) {             // B: BN/8 calls (NI/wave)
            int c = wid * NI + j;
            gload16(Bg + (size_t)(c * 8) * K + k0, Bb + c * 512);
        }
    };

    auto COMPUTE = [&](const u16* Ab, const u16* Bb) {
        #pragma unroll
        for (int kk = 0; kk < 2; kk++) {
            const int x = kk ? 32 : 0;
            half8 af[4], bf[NI];
            #pragma unroll
            for (int mi = 0; mi < 4; mi++)
                af[mi] = *(const half8*)&Ab[(aBase ^ x) + mi * 1024];
            #pragma unroll
            for (int ni = 0; ni < NI; ni++)
                bf[ni] = *(const half8*)&Bb[(bBase ^ x) + ni * 1024];
            #pragma unroll
            for (int mi = 0; mi < 4; mi++)
                #pragma unroll
                for (int ni = 0; ni < NI; ni++)
                    acc[mi][ni] = __builtin_amdgcn_mfma_f32_16x16x32_f16(af[mi], bf[ni], acc[mi][ni], 0, 0, 0);
        }
    };

    const int NT = K >> 6;                          // K/64, even for all our shapes
    STAGE(As0, Bs0, 0);
    __syncthreads();                                // drain vmcnt: tile 0 ready
    for (int t = 0; t < NT; t += 2) {
        if (t + 1 < NT) STAGE(As1, Bs1, (t + 1) << 6);
        COMPUTE(As0, Bs0);
        __syncthreads();                            // tile t+1 ready; As0 free
        if (t + 2 < NT) STAGE(As0, Bs0, (t + 2) << 6);
        if (t + 1 < NT) COMPUTE(As1, Bs1);
        __syncthreads();                            // tile t+2 ready; As1 free
    }

    const int cr = (lane >> 4) * 4;
    const int cc = lane & 15;
    #pragma unroll
    for (int mi = 0; mi < 4; mi++) {
        #pragma unroll
        for (int ni = 0; ni < NI; ni++) {
            #pragma unroll
            for (int q = 0; q < 4; q++) {
                int row = bm + wm * 64 + mi * 16 + cr + q;
                int col = bn + wn * (BN / 2) + ni * 16 + cc;
                float v = acc[mi][ni][q];
                if (EPI == 0) {
                    ((float*)C0v)[(size_t)row * N + col] = v;
                } else {
                    int half = N >> 1;
                    if (col < half) ((u16*)C0v)[(size_t)row * half + col] = f2h_bits(v);
                    else            ((u16*)C1v)[(size_t)row * half + col - half] = f2h_bits(siluf(v));
                }
            }
        }
    }
}

// ---------------- depthwise causal conv (4 taps) + bias + SiLU, fp16 io ----------------
__global__ __launch_bounds__(256)
void conv_silu16(const u16* __restrict__ xin16, const float* __restrict__ cw,
                 const float* __restrict__ cb, u16* __restrict__ xc16)
{
    int idx = blockIdx.x * 256 + threadIdx.x;      // (b,t,d8): NB*L*DIN/8
    int d8 = idx & 255;
    int t  = (idx >> 8) & (L_SEQ - 1);
    int b  = idx >> 19;
    int d  = d8 << 3;
    const float4* cw4 = (const float4*)cw;
    float4 w[8];
    #pragma unroll
    for (int j = 0; j < 8; j++) w[j] = cw4[d + j];
    float acc[8];
    {
        float4 b0 = *(const float4*)&cb[d];
        float4 b1 = *(const float4*)&cb[d + 4];
        acc[0]=b0.x; acc[1]=b0.y; acc[2]=b0.z; acc[3]=b0.w;
        acc[4]=b1.x; acc[5]=b1.y; acc[6]=b1.z; acc[7]=b1.w;
    }
    #pragma unroll
    for (int k = 0; k < 4; k++) {
        int tt = t + k - 3;
        if (tt >= 0) {
            short8 v = *(const short8*)&xin16[((size_t)(b * L_SEQ + tt)) * DIN + d];
            #pragma unroll
            for (int j = 0; j < 8; j++)
                acc[j] = fmaf(h2f((u16)v[j]), (&w[j].x)[k], acc[j]);
        }
    }
    short8 o;
    #pragma unroll
    for (int j = 0; j < 8; j++) o[j] = (short)f2h_bits(siluf(acc[j]));
    *(short8*)&xc16[(size_t)idx * 8] = o;
}

// ---------------- W_x (2048x33 fp32) -> WxT16 [48][2048] fp16, zero-padded ----------------
__global__ __launch_bounds__(256)
void transpose_wx16(const float* __restrict__ Wx, u16* __restrict__ WxT16)
{
    int idx = blockIdx.x * 256 + threadIdx.x;      // 48*2048
    int n = idx >> 11, k = idx & 2047;
    float v = (n < 33) ? Wx[k * 33 + n] : 0.f;
    WxT16[idx] = f2h_bits(v);
}

// ---------------- GEMM2: [4096][2048] @ [48][2048]^T, K-split 8, tile M=64 ----------------
__global__ __launch_bounds__(256)
void gemm2_mfma(const u16* __restrict__ A, const u16* __restrict__ Bt, float* __restrict__ pb)
{
    __shared__ __align__(16) u16 As[64 * 64];
    __shared__ __align__(16) u16 Bs[48 * 64];
    const int tid = threadIdx.x, lane = tid & 63, w = tid >> 6;
    const int bm = blockIdx.x * 64;
    const int kz = blockIdx.y;
    const int arow = tid >> 2;          // 0..63
    const int au   = (tid & 3) << 1;    // unit pair
    f32x4 acc[3];
    acc[0] = acc[1] = acc[2] = (f32x4){0.f, 0.f, 0.f, 0.f};

    for (int it = 0; it < 4; ++it) {
        const int k0 = kz * 256 + it * 64;
        short8 ra0 = *(const short8*)&A[(size_t)(bm + arow) * DIN + k0 + au * 8];
        short8 ra1 = *(const short8*)&A[(size_t)(bm + arow) * DIN + k0 + (au + 1) * 8];
        short8 rb0, rb1;
        if (tid < 192) {
            rb0 = *(const short8*)&Bt[(size_t)arow * DIN + k0 + au * 8];
            rb1 = *(const short8*)&Bt[(size_t)arow * DIN + k0 + (au + 1) * 8];
        }
        __syncthreads();
        {
            int s0 = au ^ (arow & 7), s1 = (au + 1) ^ (arow & 7);
            *(short8*)&As[arow * 64 + s0 * 8] = ra0;
            *(short8*)&As[arow * 64 + s1 * 8] = ra1;
            if (tid < 192) {
                *(short8*)&Bs[arow * 64 + s0 * 8] = rb0;
                *(short8*)&Bs[arow * 64 + s1 * 8] = rb1;
            }
        }
        __syncthreads();
        #pragma unroll
        for (int kk = 0; kk < 2; kk++) {
            int r = w * 16 + (lane & 15);
            int sl = (kk * 4 + (lane >> 4)) ^ (r & 7);
            half8 af = *(const half8*)&As[r * 64 + sl * 8];
            #pragma unroll
            for (int ni = 0; ni < 3; ni++) {
                int br = ni * 16 + (lane & 15);
                int bsl = (kk * 4 + (lane >> 4)) ^ (br & 7);
                half8 bf = *(const half8*)&Bs[br * 64 + bsl * 8];
                acc[ni] = __builtin_amdgcn_mfma_f32_16x16x32_f16(af, bf, acc[ni], 0, 0, 0);
            }
        }
    }
    #pragma unroll
    for (int ni = 0; ni < 3; ni++) {
        #pragma unroll
        for (int q = 0; q < 4; q++) {
            int row = bm + w * 16 + (lane >> 4) * 4 + q;
            int col = ni * 16 + (lane & 15);
            pb[((size_t)kz * NROWS + row) * 48 + col] = acc[ni][q];
        }
    }
}

// ---------------- GEMM2 reduce: sum 8 partials, softplus col0, split B/C ----------------
__global__ __launch_bounds__(256)
void gemm2_reduce(const float* __restrict__ pb, float* __restrict__ delta,
                  float* __restrict__ Bm, float* __restrict__ Cm)
{
    int idx = blockIdx.x * 256 + threadIdx.x;      // 4096*48
    int row = idx / 48, col = idx - row * 48;
    float s = 0.f;
    #pragma unroll
    for (int kz = 0; kz < 8; kz++) s += pb[(size_t)kz * NROWS * 48 + idx];
    if (col == 0)       delta[row] = fmaxf(s, 0.f) + log1pf(__expf(-fabsf(s)));
    else if (col < 17)  Bm[row * NST + col - 1]  = s;
    else if (col < 33)  Cm[row * NST + col - 17] = s;
}

// ---------------- scan pass 1: thread-per-d, h[16] in regs ----------------
__global__ __launch_bounds__(256)
void scan_part1_reg(const u16* __restrict__ xc16, const float* __restrict__ delta,
                    const float* __restrict__ Bm, const float* __restrict__ A_log,
                    float* __restrict__ h_loc, float* __restrict__ Pc)
{
    const int b = blockIdx.z, c = blockIdx.y;
    const int d = blockIdx.x * 256 + threadIdx.x;
    float ka[16];
    {
        const float4* Av = (const float4*)(A_log + (size_t)d * 16);
        #pragma unroll
        for (int q = 0; q < 4; q++) {
            float4 a = Av[q];
            ka[q*4+0] = -__expf(a.x) * 1.44269504f;
            ka[q*4+1] = -__expf(a.y) * 1.44269504f;
            ka[q*4+2] = -__expf(a.z) * 1.44269504f;
            ka[q*4+3] = -__expf(a.w) * 1.44269504f;
        }
    }
    float h[16];
    #pragma unroll
    for (int n = 0; n < 16; n++) h[n] = 0.f;
    float S = 0.f;
    const int rowbase = b * L_SEQ + c * CL;
    #pragma unroll 2
    for (int t = 0; t < CL; ++t) {
        const int rowg = rowbase + t;
        const float dt = delta[rowg];
        const float4* Bv = (const float4*)(Bm + (size_t)rowg * 16);
        float4 b0 = Bv[0], b1 = Bv[1], b2 = Bv[2], b3 = Bv[3];
        float bb[16] = {b0.x,b0.y,b0.z,b0.w, b1.x,b1.y,b1.z,b1.w,
                        b2.x,b2.y,b2.z,b2.w, b3.x,b3.y,b3.z,b3.w};
        const float xt = h2f(xc16[(size_t)rowg * DIN + d]);
        const float dtx = dt * xt;
        S += dt;
        #pragma unroll
        for (int n = 0; n < 16; n++) {
            float a = fexp2(dt * ka[n]);
            h[n] = fmaf(a, h[n], bb[n] * dtx);
        }
    }
    float* hp = h_loc + (((size_t)(b * NC + c) * DIN) + d) * 16;
    float* pp = Pc    + (((size_t)(b * NC + c) * DIN) + d) * 16;
    #pragma unroll
    for (int q = 0; q < 4; q++) {
        *(float4*)&hp[q*4] = (float4){h[q*4+0], h[q*4+1], h[q*4+2], h[q*4+3]};
        *(float4*)&pp[q*4] = (float4){fexp2(S*ka[q*4+0]), fexp2(S*ka[q*4+1]),
                                      fexp2(S*ka[q*4+2]), fexp2(S*ka[q*4+3])};
    }
}

// ---------------- scan pass 2: sequential carry across chunks ----------------
__global__ __launch_bounds__(256)
void scan_carry(const float* __restrict__ h_loc, const float* __restrict__ Pc,
                float* __restrict__ H_in)
{
    int gid = blockIdx.x * 256 + threadIdx.x;      // NB*DIN*NST = 65536
    int b = gid >> 15, r = gid & 32767;
    float H = 0.f;
    for (int c = 0; c < NC; ++c) {
        size_t idx = ((size_t)(b * NC + c) << 15) + r;
        H_in[idx] = H;
        H = fmaf(Pc[idx], H, h_loc[idx]);
    }
}

// ---------------- scan pass 3: thread-per-d, fused epilogue -> y fp16 ----------------
__global__ __launch_bounds__(256)
void scan_part3_reg(const u16* __restrict__ xc16, const float* __restrict__ delta,
                    const float* __restrict__ Bm, const float* __restrict__ Cm,
                    const float* __restrict__ A_log, const float* __restrict__ Dp,
                    const u16* __restrict__ res16, const float* __restrict__ H_in,
                    u16* __restrict__ yh)
{
    const int b = blockIdx.z, c = blockIdx.y;
    const int d = blockIdx.x * 256 + threadIdx.x;
    float ka[16];
    {
        const float4* Av = (const float4*)(A_log + (size_t)d * 16);
        #pragma unroll
        for (int q = 0; q < 4; q++) {
            float4 a = Av[q];
            ka[q*4+0] = -__expf(a.x) * 1.44269504f;
            ka[q*4+1] = -__expf(a.y) * 1.44269504f;
            ka[q*4+2] = -__expf(a.z) * 1.44269504f;
            ka[q*4+3] = -__expf(a.w) * 1.44269504f;
        }
    }
    float h[16];
    {
        const float4* Hv = (const float4*)(H_in + (((size_t)(b * NC + c) * DIN) + d) * 16);
        #pragma unroll
        for (int q = 0; q < 4; q++) {
            float4 v = Hv[q];
            h[q*4+0]=v.x; h[q*4+1]=v.y; h[q*4+2]=v.z; h[q*4+3]=v.w;
        }
    }
    const float Dpd = Dp[d];
    const int rowbase = b * L_SEQ + c * CL;
    #pragma unroll 2
    for (int t = 0; t < CL; ++t) {
        const int rowg = rowbase + t;
        const float dt = delta[rowg];
        const float4* Bv = (const float4*)(Bm + (size_t)rowg * 16);
        const float4* Cv = (const float4*)(Cm + (size_t)rowg * 16);
        float4 b0 = Bv[0], b1 = Bv[1], b2 = Bv[2], b3 = Bv[3];
        float4 c0 = Cv[0], c1 = Cv[1], c2 = Cv[2], c3 = Cv[3];
        float bb[16] = {b0.x,b0.y,b0.z,b0.w, b1.x,b1.y,b1.z,b1.w,
                        b2.x,b2.y,b2.z,b2.w, b3.x,b3.y,b3.z,b3.w};
        float cc[16] = {c0.x,c0.y,c0.z,c0.w, c1.x,c1.y,c1.z,c1.w,
                        c2.x,c2.y,c2.z,c2.w, c3.x,c3.y,c3.z,c3.w};
        const float xt = h2f(xc16[(size_t)rowg * DIN + d]);
        const float rt = h2f(res16[(size_t)rowg * DIN + d]);
        const float dtx = dt * xt;
        float y = 0.f;
        #pragma unroll
        for (int n = 0; n < 16; n++) {
            float a = fexp2(dt * ka[n]);
            h[n] = fmaf(a, h[n], bb[n] * dtx);
            y = fmaf(cc[n], h[n], y);
        }
        y = (y + xt * Dpd) * rt;
        yh[(size_t)rowg * DIN + d] = f2h_bits(y);
    }
}

extern "C" void kernel_launch(void* const* d_in, const int* in_sizes, int n_in,
                              void* d_out, int out_size, void* d_ws, size_t ws_size,
                              hipStream_t stream)
{
    const float* x     = (const float*)d_in[0];
    const float* W_in  = (const float*)d_in[1];
    const float* cw    = (const float*)d_in[2];
    const float* cb    = (const float*)d_in[3];
    const float* Wx    = (const float*)d_in[4];
    const float* A_log = (const float*)d_in[5];
    const float* Dp    = (const float*)d_in[6];
    const float* W_out = (const float*)d_in[7];
    float* out = (float*)d_out;
    float* ws  = (float*)d_ws;

    // workspace layout (float slot offsets)
    u16*   xin16 = (u16*)(ws);                     // [4096][2048] u16 ; later y16 alias
    u16*   y16   = (u16*)(ws);
    u16*   res16 = (u16*)(ws + 4194304);           // [4096][2048]
    u16*   xc16  = (u16*)(ws + 8388608);           // [4096][2048]
    u16*   x16   = (u16*)(ws + 12582912);          // [4096][1024] ; later Bt3 alias
    u16*   Bt3   = (u16*)(ws + 12582912);          // [1024][2048]
    u16*   Bt1   = (u16*)(ws + 14680064);          // [4096][1024] ; later pb alias
    float* pb    = ws + 14680064;                  // [8][4096][48]
    u16*   WxT16 = (u16*)(ws + 16777216);          // [48][2048]
    float* delta = ws + 16826368;                  // 4096
    float* Bm    = ws + 16830464;                  // 65536
    float* Cm    = ws + 16896000;                  // 65536
    float* h_loc = ws + 16961536;                  // 2097152
    float* Pc    = ws + 19058688;                  // 2097152
    float* H_in  = ws + 21155840;                  // 2097152 (end 23252992 floats = 93 MB)

    dim3 blk(256);

    // 1) x -> fp16
    f32_to_f16<<<dim3(NROWS * DMOD / 4 / 256), blk, 0, stream>>>(x, x16, NROWS * DMOD / 4);
    // 2) W_in (1024x4096) -> Bt1 (4096x1024) fp16
    transpose_to_f16<<<dim3(4096 / 64, 1024 / 64), blk, 0, stream>>>(W_in, Bt1, DMOD, 2 * DIN);
    // 3) GEMM1 -> xin16 | silu(res)16
    gemm_mfma<128, 1><<<dim3(32, 32), blk, 0, stream>>>(x16, Bt1, xin16, res16, NROWS, 2 * DIN, DMOD);
    // 4) conv + bias + silu (fp16 io)
    conv_silu16<<<dim3(NB * L_SEQ * (DIN / 8) / 256), blk, 0, stream>>>(xin16, cw, cb, xc16);
    // 5) ssm params: W_x^T fp16 (pad 48), MFMA K-split GEMM, reduce+softplus
    transpose_wx16<<<dim3(48 * DIN / 256), blk, 0, stream>>>(Wx, WxT16);
    gemm2_mfma<<<dim3(NROWS / 64, 8), blk, 0, stream>>>(xc16, WxT16, pb);
    gemm2_reduce<<<dim3(NROWS * 48 / 256), blk, 0, stream>>>(pb, delta, Bm, Cm);
    // 6) chunk-parallel scan (thread-per-d, regs), CL=64
    scan_part1_reg<<<dim3(DIN / 256, NC, NB), blk, 0, stream>>>(xc16, delta, Bm, A_log, h_loc, Pc);
    scan_carry<<<dim3(NB * DIN * NST / 256), blk, 0, stream>>>(h_loc, Pc, H_in);
    scan_part3_reg<<<dim3(DIN / 256, NC, NB), blk, 0, stream>>>(xc16, delta, Bm, Cm, A_log, Dp, res16, H_in, y16);
    // 7) W_out (2048x1024) -> Bt3 (1024x2048) fp16
    transpose_to_f16<<<dim3(1024 / 64, 2048 / 64), blk, 0, stream>>>(W_out, Bt3, DIN, DMOD);
    // 8) GEMM3: out = y @ W_out (fp32 out), BN=64 tiles -> 512 blocks
    gemm_mfma<64, 0><<<dim3(1024 / 64, NROWS / 128), blk, 0, stream>>>(y16, Bt3, out, nullptr, NROWS, DMOD, DIN);
}